// Round 1
// baseline (6440.163 us; speedup 1.0000x reference)
//
#include <hip/hip_runtime.h>
#include <hip/hip_bf16.h>
#include <math.h>

// ModularRegimeRNN forward: B=4096, D=512, H=1024, K=8 experts, NH=4 heads, O=256.
// Round 1: correct fp32 baseline. Heavy GEMMs use 64x64 LDS tiles, 4x4/thread.
// Outputs concat: h_new (B,K,H) | y_hat (B,O) | g_t (B,K) | logits (B,K), all f32.

#define B_  4096
#define D_  512
#define H_  1024
#define K_  8
#define O_  256
#define NH_ 4
#define HD_ 256
#define H3_ 3072

__device__ __forceinline__ float sigmoidf_(float x) {
    return 1.0f / (1.0f + __expf(-x));
}

// ---------------------------------------------------------------------------
// Fused GRU: for expert k, tile (64 b) x (64 e). Accumulates
//   racc = x@Wih_r + hp@Whh_r,  zacc = x@Wih_z + hp@Whh_z,
//   iacc = x@Wih_n,             hacc = hp@Whh_n
// then epilogue: r=sig, z=sig, n=tanh(i_n + r*h_n), h=(1-z)n+z*hp -> d_out (pre-LN)
// ---------------------------------------------------------------------------
__global__ __launch_bounds__(256)
void gru_kernel(const float* __restrict__ x, const float* __restrict__ hp,
                const float* __restrict__ Wih, const float* __restrict__ Whh,
                const float* __restrict__ bih, const float* __restrict__ bhh,
                float* __restrict__ hout)
{
    __shared__ __align__(16) float As[16][68];
    __shared__ __align__(16) float Wr[16][68];
    __shared__ __align__(16) float Wz[16][68];
    __shared__ __align__(16) float Wn[16][68];

    const int tid = threadIdx.x;
    const int tx = tid & 15, ty = tid >> 4;
    const int b0 = blockIdx.x * 64;
    const int n0 = blockIdx.y * 64;
    const int k  = blockIdx.z;

    float racc[4][4] = {{0.f}}, zacc[4][4] = {{0.f}};
    float iacc[4][4] = {{0.f}}, hacc[4][4] = {{0.f}};

    const int lm = tid >> 2;        // 0..63: row within tile (loader)
    const int lk = (tid & 3) * 4;   // 0,4,8,12: k-offset (loader, float4)

    // ---- phase 1: input gates, Kd = D_ = 512 ----
    {
        const float* Arow  = x   + (size_t)(b0 + lm) * D_ + lk;
        const float* WrRow = Wih + ((size_t)k * H3_ + (n0 + lm)) * D_ + lk;
        const float* WzRow = WrRow + (size_t)H_ * D_;
        const float* WnRow = WrRow + (size_t)(2 * H_) * D_;
        for (int kt = 0; kt < D_; kt += 16) {
            float4 a = *(const float4*)(Arow + kt);
            float4 r = *(const float4*)(WrRow + kt);
            float4 z = *(const float4*)(WzRow + kt);
            float4 n = *(const float4*)(WnRow + kt);
            As[lk+0][lm] = a.x; As[lk+1][lm] = a.y; As[lk+2][lm] = a.z; As[lk+3][lm] = a.w;
            Wr[lk+0][lm] = r.x; Wr[lk+1][lm] = r.y; Wr[lk+2][lm] = r.z; Wr[lk+3][lm] = r.w;
            Wz[lk+0][lm] = z.x; Wz[lk+1][lm] = z.y; Wz[lk+2][lm] = z.z; Wz[lk+3][lm] = z.w;
            Wn[lk+0][lm] = n.x; Wn[lk+1][lm] = n.y; Wn[lk+2][lm] = n.z; Wn[lk+3][lm] = n.w;
            __syncthreads();
            #pragma unroll
            for (int kk = 0; kk < 16; ++kk) {
                const float4 av = *(const float4*)(&As[kk][ty * 4]);
                const float4 rv = *(const float4*)(&Wr[kk][tx * 4]);
                const float4 zv = *(const float4*)(&Wz[kk][tx * 4]);
                const float4 nv = *(const float4*)(&Wn[kk][tx * 4]);
                const float aa[4] = {av.x, av.y, av.z, av.w};
                const float rr[4] = {rv.x, rv.y, rv.z, rv.w};
                const float zz[4] = {zv.x, zv.y, zv.z, zv.w};
                const float nn[4] = {nv.x, nv.y, nv.z, nv.w};
                #pragma unroll
                for (int i = 0; i < 4; ++i)
                    #pragma unroll
                    for (int j = 0; j < 4; ++j) {
                        racc[i][j] = fmaf(aa[i], rr[j], racc[i][j]);
                        zacc[i][j] = fmaf(aa[i], zz[j], zacc[i][j]);
                        iacc[i][j] = fmaf(aa[i], nn[j], iacc[i][j]);
                    }
            }
            __syncthreads();
        }
    }

    // ---- phase 2: hidden gates, Kd = H_ = 1024 ----
    {
        const float* Arow  = hp  + ((size_t)(b0 + lm) * K_ + k) * H_ + lk;
        const float* WrRow = Whh + ((size_t)k * H3_ + (n0 + lm)) * H_ + lk;
        const float* WzRow = WrRow + (size_t)H_ * H_;
        const float* WnRow = WrRow + (size_t)(2 * H_) * H_;
        for (int kt = 0; kt < H_; kt += 16) {
            float4 a = *(const float4*)(Arow + kt);
            float4 r = *(const float4*)(WrRow + kt);
            float4 z = *(const float4*)(WzRow + kt);
            float4 n = *(const float4*)(WnRow + kt);
            As[lk+0][lm] = a.x; As[lk+1][lm] = a.y; As[lk+2][lm] = a.z; As[lk+3][lm] = a.w;
            Wr[lk+0][lm] = r.x; Wr[lk+1][lm] = r.y; Wr[lk+2][lm] = r.z; Wr[lk+3][lm] = r.w;
            Wz[lk+0][lm] = z.x; Wz[lk+1][lm] = z.y; Wz[lk+2][lm] = z.z; Wz[lk+3][lm] = z.w;
            Wn[lk+0][lm] = n.x; Wn[lk+1][lm] = n.y; Wn[lk+2][lm] = n.z; Wn[lk+3][lm] = n.w;
            __syncthreads();
            #pragma unroll
            for (int kk = 0; kk < 16; ++kk) {
                const float4 av = *(const float4*)(&As[kk][ty * 4]);
                const float4 rv = *(const float4*)(&Wr[kk][tx * 4]);
                const float4 zv = *(const float4*)(&Wz[kk][tx * 4]);
                const float4 nv = *(const float4*)(&Wn[kk][tx * 4]);
                const float aa[4] = {av.x, av.y, av.z, av.w};
                const float rr[4] = {rv.x, rv.y, rv.z, rv.w};
                const float zz[4] = {zv.x, zv.y, zv.z, zv.w};
                const float nn[4] = {nv.x, nv.y, nv.z, nv.w};
                #pragma unroll
                for (int i = 0; i < 4; ++i)
                    #pragma unroll
                    for (int j = 0; j < 4; ++j) {
                        racc[i][j] = fmaf(aa[i], rr[j], racc[i][j]);
                        zacc[i][j] = fmaf(aa[i], zz[j], zacc[i][j]);
                        hacc[i][j] = fmaf(aa[i], nn[j], hacc[i][j]);
                    }
            }
            __syncthreads();
        }
    }

    // ---- epilogue: GRU pointwise, write pre-LN h_new ----
    const float* bi = bih + (size_t)k * H3_;
    const float* bh = bhh + (size_t)k * H3_;
    #pragma unroll
    for (int i = 0; i < 4; ++i) {
        const int b = b0 + ty * 4 + i;
        const size_t rowbase = ((size_t)b * K_ + k) * H_;
        float o[4];
        #pragma unroll
        for (int j = 0; j < 4; ++j) {
            const int e = n0 + tx * 4 + j;
            const float gr = racc[i][j] + bi[e]        + bh[e];
            const float gz = zacc[i][j] + bi[e + H_]   + bh[e + H_];
            const float r = sigmoidf_(gr);
            const float z = sigmoidf_(gz);
            const float nn = tanhf(iacc[i][j] + bi[e + 2*H_] + r * (hacc[i][j] + bh[e + 2*H_]));
            const float hv = hp[rowbase + e];
            o[j] = (1.0f - z) * nn + z * hv;
        }
        *(float4*)(&hout[rowbase + n0 + tx * 4]) = make_float4(o[0], o[1], o[2], o[3]);
    }
}

// ---------------------------------------------------------------------------
// Generic NT GEMM: C[M,N] = A[M,Kd] @ B[N,Kd]^T + bias[N]. Kd % 16 == 0.
// ---------------------------------------------------------------------------
__global__ __launch_bounds__(256)
void gemm_nt(const float* __restrict__ A, const float* __restrict__ Bm,
             const float* __restrict__ bias, float* __restrict__ C,
             int M, int N, int Kd)
{
    __shared__ __align__(16) float As[16][68];
    __shared__ __align__(16) float Bs[16][68];

    const int tid = threadIdx.x;
    const int tx = tid & 15, ty = tid >> 4;
    const int m0 = blockIdx.x * 64;
    const int n0 = blockIdx.y * 64;

    float acc[4][4] = {{0.f}};

    const int lm = tid >> 2;
    const int lk = (tid & 3) * 4;
    const int arow = m0 + lm;
    const int brow = n0 + lm;
    const bool aval = arow < M;
    const bool bval = brow < N;
    const float* Ap = A  + (size_t)arow * Kd + lk;
    const float* Bp = Bm + (size_t)brow * Kd + lk;

    for (int kt = 0; kt < Kd; kt += 16) {
        float4 a = aval ? *(const float4*)(Ap + kt) : make_float4(0.f, 0.f, 0.f, 0.f);
        float4 b = bval ? *(const float4*)(Bp + kt) : make_float4(0.f, 0.f, 0.f, 0.f);
        As[lk+0][lm] = a.x; As[lk+1][lm] = a.y; As[lk+2][lm] = a.z; As[lk+3][lm] = a.w;
        Bs[lk+0][lm] = b.x; Bs[lk+1][lm] = b.y; Bs[lk+2][lm] = b.z; Bs[lk+3][lm] = b.w;
        __syncthreads();
        #pragma unroll
        for (int kk = 0; kk < 16; ++kk) {
            const float4 av = *(const float4*)(&As[kk][ty * 4]);
            const float4 bv = *(const float4*)(&Bs[kk][tx * 4]);
            const float aa[4] = {av.x, av.y, av.z, av.w};
            const float bb[4] = {bv.x, bv.y, bv.z, bv.w};
            #pragma unroll
            for (int i = 0; i < 4; ++i)
                #pragma unroll
                for (int j = 0; j < 4; ++j)
                    acc[i][j] = fmaf(aa[i], bb[j], acc[i][j]);
        }
        __syncthreads();
    }

    #pragma unroll
    for (int i = 0; i < 4; ++i) {
        const int r = m0 + ty * 4 + i;
        if (r >= M) continue;
        const int c0 = n0 + tx * 4;
        if (c0 + 3 < N) {
            float4 o;
            o.x = acc[i][0] + bias[c0 + 0];
            o.y = acc[i][1] + bias[c0 + 1];
            o.z = acc[i][2] + bias[c0 + 2];
            o.w = acc[i][3] + bias[c0 + 3];
            *(float4*)(&C[(size_t)r * N + c0]) = o;
        } else {
            #pragma unroll
            for (int j = 0; j < 4; ++j) {
                const int c = c0 + j;
                if (c < N) C[(size_t)r * N + c] = acc[i][j] + bias[c];
            }
        }
    }
}

// ---------------------------------------------------------------------------
// Block-wide sum of (s, s2) over 256 threads (4 waves).
// ---------------------------------------------------------------------------
__device__ __forceinline__ void block_sum2(float& s, float& s2, float* red, int tid)
{
    #pragma unroll
    for (int off = 32; off > 0; off >>= 1) {
        s  += __shfl_down(s,  off);
        s2 += __shfl_down(s2, off);
    }
    const int wid = tid >> 6;
    if ((tid & 63) == 0) { red[wid] = s; red[4 + wid] = s2; }
    __syncthreads();
    if (tid == 0) {
        float a = 0.f, b = 0.f;
        for (int i = 0; i < 4; ++i) { a += red[i]; b += red[4 + i]; }
        red[8] = a; red[9] = b;
    }
    __syncthreads();
    s = red[8]; s2 = red[9];
}

// LN over H=1024 per (b,k) row of h_new, in place. gamma/beta indexed by expert.
__global__ __launch_bounds__(256)
void ln_expert_kernel(float* __restrict__ h, const float* __restrict__ g,
                      const float* __restrict__ bb)
{
    __shared__ float red[10];
    const int row = blockIdx.x;       // b*K + k
    const int k = row & (K_ - 1);
    const int tid = threadIdx.x;
    float* p = h + (size_t)row * H_;

    const float4 v = *(const float4*)(p + tid * 4);
    float s  = v.x + v.y + v.z + v.w;
    float s2 = v.x * v.x + v.y * v.y + v.z * v.z + v.w * v.w;
    block_sum2(s, s2, red, tid);
    const float mean = s * (1.0f / H_);
    const float var  = s2 * (1.0f / H_) - mean * mean;
    const float inv  = rsqrtf(var + 1e-5f);

    const float* gg = g  + (size_t)k * H_ + tid * 4;
    const float* bp = bb + (size_t)k * H_ + tid * 4;
    float4 o;
    o.x = (v.x - mean) * inv * gg[0] + bp[0];
    o.y = (v.y - mean) * inv * gg[1] + bp[1];
    o.z = (v.z - mean) * inv * gg[2] + bp[2];
    o.w = (v.w - mean) * inv * gg[3] + bp[3];
    *(float4*)(p + tid * 4) = o;
}

// context = LN(query + attn_out) with aln_g/aln_b (shared across rows)
__global__ __launch_bounds__(256)
void add_ln_kernel(const float* __restrict__ q, const float* __restrict__ a,
                   const float* __restrict__ g, const float* __restrict__ bb,
                   float* __restrict__ out)
{
    __shared__ float red[10];
    const int row = blockIdx.x;       // b
    const int tid = threadIdx.x;
    const float4 qv = *(const float4*)(q + (size_t)row * H_ + tid * 4);
    const float4 av = *(const float4*)(a + (size_t)row * H_ + tid * 4);
    float4 v = make_float4(qv.x + av.x, qv.y + av.y, qv.z + av.z, qv.w + av.w);
    float s  = v.x + v.y + v.z + v.w;
    float s2 = v.x * v.x + v.y * v.y + v.z * v.z + v.w * v.w;
    block_sum2(s, s2, red, tid);
    const float mean = s * (1.0f / H_);
    const float var  = s2 * (1.0f / H_) - mean * mean;
    const float inv  = rsqrtf(var + 1e-5f);
    const float* gg = g  + tid * 4;
    const float* bp = bb + tid * 4;
    float4 o;
    o.x = (v.x - mean) * inv * gg[0] + bp[0];
    o.y = (v.y - mean) * inv * gg[1] + bp[1];
    o.z = (v.z - mean) * inv * gg[2] + bp[2];
    o.w = (v.w - mean) * inv * gg[3] + bp[3];
    *(float4*)(out + (size_t)row * H_ + tid * 4) = o;
}

// ---------------------------------------------------------------------------
// Attention over K=8 expert states, NH=4 heads of HD=256. One block per b.
// ---------------------------------------------------------------------------
__global__ __launch_bounds__(256)
void attn_kernel(const float* __restrict__ q, const float* __restrict__ kb,
                 const float* __restrict__ vb, float* __restrict__ ctx)
{
    __shared__ __align__(16) float qs[H_];
    __shared__ float sc[NH_ * K_];
    __shared__ float aw[NH_ * K_];
    const int b = blockIdx.x;
    const int tid = threadIdx.x;

    *(float4*)(&qs[tid * 4]) = *(const float4*)(q + (size_t)b * H_ + tid * 4);
    __syncthreads();

    // scores[nh][kx] = (q_head . k_head) / sqrt(HD); 8 threads per (nh,kx) pair
    const int pair = tid >> 3;        // 0..31
    const int l8 = tid & 7;
    const int nh = pair >> 3;         // 0..3
    const int kx = pair & 7;          // 0..7
    float partial = 0.f;
    const float* kr = kb + ((size_t)b * K_ + kx) * H_ + nh * HD_;
    #pragma unroll
    for (int t = 0; t < 8; ++t) {
        const int off = (l8 + t * 8) * 4;
        const float4 qq = *(const float4*)(&qs[nh * HD_ + off]);
        const float4 kk = *(const float4*)(kr + off);
        partial += qq.x * kk.x + qq.y * kk.y + qq.z * kk.z + qq.w * kk.w;
    }
    partial += __shfl_down(partial, 4, 8);
    partial += __shfl_down(partial, 2, 8);
    partial += __shfl_down(partial, 1, 8);
    if (l8 == 0) sc[pair] = partial * (1.0f / 16.0f);   // 1/sqrt(256)
    __syncthreads();

    // softmax over kx per head
    if (tid < NH_) {
        float m = -1e30f;
        for (int j = 0; j < K_; ++j) m = fmaxf(m, sc[tid * K_ + j]);
        float e[K_]; float ssum = 0.f;
        for (int j = 0; j < K_; ++j) { e[j] = __expf(sc[tid * K_ + j] - m); ssum += e[j]; }
        const float invs = 1.0f / ssum;
        for (int j = 0; j < K_; ++j) aw[tid * K_ + j] = e[j] * invs;
    }
    __syncthreads();

    // ctx[h] = sum_kx aw * v; 4 elems per thread
    const int e0 = tid * 4;
    const int nh2 = e0 >> 8;
    float4 acc = make_float4(0.f, 0.f, 0.f, 0.f);
    #pragma unroll
    for (int j = 0; j < K_; ++j) {
        const float w = aw[nh2 * K_ + j];
        const float4 v4 = *(const float4*)(vb + ((size_t)b * K_ + j) * H_ + e0);
        acc.x += w * v4.x; acc.y += w * v4.y; acc.z += w * v4.z; acc.w += w * v4.w;
    }
    *(float4*)(ctx + (size_t)b * H_ + e0) = acc;
}

// softmax over K=8 logits per row
__global__ __launch_bounds__(256)
void gate_softmax_kernel(const float* __restrict__ logits, float* __restrict__ g)
{
    const int b = blockIdx.x * blockDim.x + threadIdx.x;
    if (b >= B_) return;
    float v[K_];
    float m = -1e30f;
    #pragma unroll
    for (int j = 0; j < K_; ++j) { v[j] = logits[(size_t)b * K_ + j]; m = fmaxf(m, v[j]); }
    float ssum = 0.f;
    #pragma unroll
    for (int j = 0; j < K_; ++j) { v[j] = __expf(v[j] - m); ssum += v[j]; }
    const float invs = 1.0f / ssum;
    #pragma unroll
    for (int j = 0; j < K_; ++j) g[(size_t)b * K_ + j] = v[j] * invs;
}

// mixed[b,h] = sum_k g[b,k] * h_new[b,k,h]
__global__ __launch_bounds__(256)
void mixed_kernel(const float* __restrict__ g, const float* __restrict__ h,
                  float* __restrict__ mixed)
{
    __shared__ float gs[K_];
    const int b = blockIdx.x;
    const int tid = threadIdx.x;
    if (tid < K_) gs[tid] = g[(size_t)b * K_ + tid];
    __syncthreads();
    const int e0 = tid * 4;
    float4 acc = make_float4(0.f, 0.f, 0.f, 0.f);
    #pragma unroll
    for (int j = 0; j < K_; ++j) {
        const float w = gs[j];
        const float4 v4 = *(const float4*)(h + ((size_t)b * K_ + j) * H_ + e0);
        acc.x += w * v4.x; acc.y += w * v4.y; acc.z += w * v4.z; acc.w += w * v4.w;
    }
    *(float4*)(mixed + (size_t)b * H_ + e0) = acc;
}

// ---------------------------------------------------------------------------
extern "C" void kernel_launch(void* const* d_in, const int* in_sizes, int n_in,
                              void* d_out, int out_size, void* d_ws, size_t ws_size,
                              hipStream_t stream)
{
    (void)in_sizes; (void)n_in; (void)out_size; (void)ws_size;

    const float* x    = (const float*)d_in[0];
    const float* hp   = (const float*)d_in[1];
    const float* Wih  = (const float*)d_in[2];
    const float* Whh  = (const float*)d_in[3];
    const float* bih  = (const float*)d_in[4];
    const float* bhh  = (const float*)d_in[5];
    const float* lng  = (const float*)d_in[6];
    const float* lnb  = (const float*)d_in[7];
    const float* Wqp  = (const float*)d_in[8];
    const float* bqp  = (const float*)d_in[9];
    const float* Wq   = (const float*)d_in[10];
    const float* Wk   = (const float*)d_in[11];
    const float* Wv   = (const float*)d_in[12];
    const float* bq   = (const float*)d_in[13];
    const float* bk   = (const float*)d_in[14];
    const float* bv   = (const float*)d_in[15];
    const float* Wo   = (const float*)d_in[16];
    const float* bo   = (const float*)d_in[17];
    const float* alng = (const float*)d_in[18];
    const float* alnb = (const float*)d_in[19];
    const float* Wg   = (const float*)d_in[20];
    const float* bg   = (const float*)d_in[21];
    const float* Wr   = (const float*)d_in[22];
    const float* br   = (const float*)d_in[23];

    float* h_new  = (float*)d_out;                         // (B,K,H)
    float* y_hat  = h_new + (size_t)B_ * K_ * H_;          // (B,O)
    float* g_t    = y_hat + (size_t)B_ * O_;               // (B,K)
    float* logits = g_t + (size_t)B_ * K_;                 // (B,K)

    // workspace layout (fp32): 6*B*H + 2*B*K*H floats = 369 MB
    float* ws     = (float*)d_ws;
    float* query  = ws;                                    // (B,H)
    float* qbuf   = query + (size_t)B_ * H_;               // (B,H)
    float* ctx    = qbuf  + (size_t)B_ * H_;               // (B,H)
    float* attno  = ctx   + (size_t)B_ * H_;               // (B,H)
    float* contx  = attno + (size_t)B_ * H_;               // (B,H)
    float* mixed  = contx + (size_t)B_ * H_;               // (B,H)
    float* kbuf   = mixed + (size_t)B_ * H_;               // (B,K,H)
    float* vbuf   = kbuf  + (size_t)B_ * K_ * H_;          // (B,K,H)

    const dim3 blk(256);

    // 1) GRU cell (pre-LN h_new into d_out)
    gru_kernel<<<dim3(B_ / 64, H_ / 64, K_), blk, 0, stream>>>(x, hp, Wih, Whh, bih, bhh, h_new);
    // 2) per-expert LayerNorm, in place
    ln_expert_kernel<<<dim3(B_ * K_), blk, 0, stream>>>(h_new, lng, lnb);
    // 3) projections
    gemm_nt<<<dim3(B_ / 64, H_ / 64), blk, 0, stream>>>(x,     Wqp, bqp, query, B_,      H_, D_);
    gemm_nt<<<dim3(B_ / 64, H_ / 64), blk, 0, stream>>>(query, Wq,  bq,  qbuf,  B_,      H_, H_);
    gemm_nt<<<dim3(B_ * K_ / 64, H_ / 64), blk, 0, stream>>>(h_new, Wk, bk, kbuf, B_ * K_, H_, H_);
    gemm_nt<<<dim3(B_ * K_ / 64, H_ / 64), blk, 0, stream>>>(h_new, Wv, bv, vbuf, B_ * K_, H_, H_);
    // 4) attention over experts
    attn_kernel<<<dim3(B_), blk, 0, stream>>>(qbuf, kbuf, vbuf, ctx);
    gemm_nt<<<dim3(B_ / 64, H_ / 64), blk, 0, stream>>>(ctx, Wo, bo, attno, B_, H_, H_);
    add_ln_kernel<<<dim3(B_), blk, 0, stream>>>(query, attno, alng, alnb, contx);
    // 5) gating + readout
    gemm_nt<<<dim3(B_ / 64, 1), blk, 0, stream>>>(contx, Wg, bg, logits, B_, K_, H_);
    gate_softmax_kernel<<<dim3(B_ / 256), blk, 0, stream>>>(logits, g_t);
    mixed_kernel<<<dim3(B_), blk, 0, stream>>>(g_t, h_new, mixed);
    gemm_nt<<<dim3(B_ / 64, O_ / 64), blk, 0, stream>>>(mixed, Wr, br, y_hat, B_, O_, H_);
}

// Round 2
// 1471.834 us; speedup vs baseline: 4.3756x; 4.3756x over previous
//
#include <hip/hip_runtime.h>
#include <hip/hip_bf16.h>
#include <math.h>

// ModularRegimeRNN forward: B=4096, D=512, H=1024, K=8, NH=4, O=256.
// Round 2: bf16 MFMA (16x16x32) for GRU + all heavy projections, fp32 accum.
// global_load_lds width=16 staging (m97 recipe). Outputs fp32.

#define B_  4096
#define D_  512
#define H_  1024
#define K_  8
#define O_  256
#define NH_ 4
#define HD_ 256
#define H3_ 3072

typedef __bf16 bf16x8 __attribute__((ext_vector_type(8)));
typedef __bf16 bf16x4 __attribute__((ext_vector_type(4)));
typedef float  f32x4  __attribute__((ext_vector_type(4)));

__device__ __forceinline__ float sigmoidf_(float x) {
    return 1.0f / (1.0f + __expf(-x));
}

// async global->LDS, 16B per lane; lds dest = wave-uniform base + lane*16
__device__ __forceinline__ void gld16(const void* g, void* l) {
    __builtin_amdgcn_global_load_lds((const __attribute__((address_space(1))) unsigned*)g,
                                     (__attribute__((address_space(3))) unsigned*)l,
                                     16, 0, 0);
}

// ---------------------------------------------------------------------------
// fp32 -> bf16 cast, 8 elems/thread, n % 8 == 0
// ---------------------------------------------------------------------------
__global__ __launch_bounds__(256)
void cast_kernel(const float* __restrict__ in, __bf16* __restrict__ out, long n)
{
    const long i = ((long)blockIdx.x * 256 + threadIdx.x) * 8;
    if (i >= n) return;
    const float4 v0 = *(const float4*)(in + i);
    const float4 v1 = *(const float4*)(in + i + 4);
    bf16x8 o;
    o[0] = (__bf16)v0.x; o[1] = (__bf16)v0.y; o[2] = (__bf16)v0.z; o[3] = (__bf16)v0.w;
    o[4] = (__bf16)v1.x; o[5] = (__bf16)v1.y; o[6] = (__bf16)v1.z; o[7] = (__bf16)v1.w;
    *(bf16x8*)(out + i) = o;
}

// ---------------------------------------------------------------------------
// MFMA GRU: 64x64 (b,e) tile per block, 4 waves in 2x2, each wave 32x32 region
// (2x2 MFMA tiles). 4 accumulator sets: r, z, i_n (x-phase), h_n (h-phase).
// ---------------------------------------------------------------------------
__global__ __launch_bounds__(256)
void gru_mfma_kernel(const __bf16* __restrict__ xbf, const __bf16* __restrict__ hpbf,
                     const __bf16* __restrict__ Wihbf, const __bf16* __restrict__ Whhbf,
                     const float* __restrict__ bih, const float* __restrict__ bhh,
                     const float* __restrict__ hp, float* __restrict__ hout)
{
    __shared__ __bf16 As[64 * 32];        // 4 KB
    __shared__ __bf16 Bs[3][64 * 32];     // 12 KB

    const int tid  = threadIdx.x;
    const int w    = tid >> 6;            // wave 0..3
    const int lane = tid & 63;
    const int wm = w >> 1, wn = w & 1;
    const int b0 = blockIdx.x * 64;
    const int n0 = blockIdx.y * 64;
    const int k  = blockIdx.z;

    f32x4 acc[4][2][2];                   // [gate r,z,in,hn][mt][nt]
    #pragma unroll
    for (int g = 0; g < 4; ++g)
        #pragma unroll
        for (int a = 0; a < 2; ++a)
            #pragma unroll
            for (int b = 0; b < 2; ++b)
                acc[g][a][b] = (f32x4){0.f, 0.f, 0.f, 0.f};

    const int lrow = lane >> 2;           // 0..15
    const int lcol = (lane & 3) * 8;      // 0,8,16,24 (bf16 elems)

    __bf16* Al  = &As[(w * 16) * 32];
    __bf16* Bl0 = &Bs[0][(w * 16) * 32];
    __bf16* Bl1 = &Bs[1][(w * 16) * 32];
    __bf16* Bl2 = &Bs[2][(w * 16) * 32];

    const int fr = lane & 15;
    const int fq = (lane >> 4) * 8;

    // ---------- phase 1: x @ Wih^T, Kd = 512; gates r,z,i_n ----------
    {
        const __bf16* Ag  = xbf + (size_t)(b0 + w * 16 + lrow) * D_ + lcol;
        const size_t wrow = (size_t)k * H3_ + n0 + w * 16 + lrow;
        const __bf16* Bg0 = Wihbf + (wrow) * D_ + lcol;
        const __bf16* Bg1 = Wihbf + (wrow + H_) * D_ + lcol;
        const __bf16* Bg2 = Wihbf + (wrow + 2 * H_) * D_ + lcol;
        for (int kt = 0; kt < D_; kt += 32) {
            gld16(Ag + kt, Al);
            gld16(Bg0 + kt, Bl0);
            gld16(Bg1 + kt, Bl1);
            gld16(Bg2 + kt, Bl2);
            __syncthreads();
            const bf16x8 a0 = *(const bf16x8*)(&As[(wm * 32 + fr) * 32 + fq]);
            const bf16x8 a1 = *(const bf16x8*)(&As[(wm * 32 + 16 + fr) * 32 + fq]);
            #pragma unroll
            for (int g = 0; g < 3; ++g) {
                const bf16x8 bA = *(const bf16x8*)(&Bs[g][(wn * 32 + fr) * 32 + fq]);
                const bf16x8 bB = *(const bf16x8*)(&Bs[g][(wn * 32 + 16 + fr) * 32 + fq]);
                acc[g][0][0] = __builtin_amdgcn_mfma_f32_16x16x32_bf16(a0, bA, acc[g][0][0], 0, 0, 0);
                acc[g][0][1] = __builtin_amdgcn_mfma_f32_16x16x32_bf16(a0, bB, acc[g][0][1], 0, 0, 0);
                acc[g][1][0] = __builtin_amdgcn_mfma_f32_16x16x32_bf16(a1, bA, acc[g][1][0], 0, 0, 0);
                acc[g][1][1] = __builtin_amdgcn_mfma_f32_16x16x32_bf16(a1, bB, acc[g][1][1], 0, 0, 0);
            }
            __syncthreads();
        }
    }

    // ---------- phase 2: hp @ Whh^T, Kd = 1024; gates r,z,h_n ----------
    {
        const __bf16* Ag  = hpbf + ((size_t)(b0 + w * 16 + lrow) * K_ + k) * H_ + lcol;
        const size_t wrow = (size_t)k * H3_ + n0 + w * 16 + lrow;
        const __bf16* Bg0 = Whhbf + (wrow) * H_ + lcol;
        const __bf16* Bg1 = Whhbf + (wrow + H_) * H_ + lcol;
        const __bf16* Bg2 = Whhbf + (wrow + 2 * H_) * H_ + lcol;
        for (int kt = 0; kt < H_; kt += 32) {
            gld16(Ag + kt, Al);
            gld16(Bg0 + kt, Bl0);
            gld16(Bg1 + kt, Bl1);
            gld16(Bg2 + kt, Bl2);
            __syncthreads();
            const bf16x8 a0 = *(const bf16x8*)(&As[(wm * 32 + fr) * 32 + fq]);
            const bf16x8 a1 = *(const bf16x8*)(&As[(wm * 32 + 16 + fr) * 32 + fq]);
            #pragma unroll
            for (int g = 0; g < 3; ++g) {
                const int gd = (g == 2) ? 3 : g;    // n-gate -> hacc slot
                const bf16x8 bA = *(const bf16x8*)(&Bs[g][(wn * 32 + fr) * 32 + fq]);
                const bf16x8 bB = *(const bf16x8*)(&Bs[g][(wn * 32 + 16 + fr) * 32 + fq]);
                acc[gd][0][0] = __builtin_amdgcn_mfma_f32_16x16x32_bf16(a0, bA, acc[gd][0][0], 0, 0, 0);
                acc[gd][0][1] = __builtin_amdgcn_mfma_f32_16x16x32_bf16(a0, bB, acc[gd][0][1], 0, 0, 0);
                acc[gd][1][0] = __builtin_amdgcn_mfma_f32_16x16x32_bf16(a1, bA, acc[gd][1][0], 0, 0, 0);
                acc[gd][1][1] = __builtin_amdgcn_mfma_f32_16x16x32_bf16(a1, bB, acc[gd][1][1], 0, 0, 0);
            }
            __syncthreads();
        }
    }

    // ---------- epilogue: GRU pointwise, write pre-LN h_new ----------
    const float* bi = bih + (size_t)k * H3_;
    const float* bh = bhh + (size_t)k * H3_;
    const int col   = lane & 15;
    const int rbase = (lane >> 4) * 4;
    #pragma unroll
    for (int nt = 0; nt < 2; ++nt) {
        const int e = n0 + wn * 32 + nt * 16 + col;
        const float bir = bi[e],          bhr = bh[e];
        const float biz = bi[H_ + e],     bhz = bh[H_ + e];
        const float bin = bi[2 * H_ + e], bhn = bh[2 * H_ + e];
        #pragma unroll
        for (int mt = 0; mt < 2; ++mt) {
            #pragma unroll
            for (int r = 0; r < 4; ++r) {
                const int b = b0 + wm * 32 + mt * 16 + rbase + r;
                const size_t rowb = ((size_t)b * K_ + k) * H_;
                const float gr = acc[0][mt][nt][r] + bir + bhr;
                const float gz = acc[1][mt][nt][r] + biz + bhz;
                const float rr = sigmoidf_(gr);
                const float zz = sigmoidf_(gz);
                const float nn = tanhf(acc[2][mt][nt][r] + bin + rr * (acc[3][mt][nt][r] + bhn));
                const float hv = hp[rowb + e];
                hout[rowb + e] = (1.0f - zz) * nn + zz * hv;
            }
        }
    }
}

// ---------------------------------------------------------------------------
// Generic MFMA NT GEMM: C[M,N] = A[M,Kd] @ W[N,Kd]^T + bias. bf16 in, fp32 acc.
// 128x128 tile, 4 waves each 64x64 (4x4 MFMA tiles). M%128==0, N%128==0, Kd%32==0.
// Cf (fp32) and/or Cb (bf16) outputs, either may be null.
// ---------------------------------------------------------------------------
__global__ __launch_bounds__(256)
void gemm_mfma(const __bf16* __restrict__ A, const __bf16* __restrict__ Wm,
               const float* __restrict__ bias, float* __restrict__ Cf,
               __bf16* __restrict__ Cb, int M, int N, int Kd)
{
    __shared__ __bf16 As[128 * 32];       // 8 KB
    __shared__ __bf16 Bs[128 * 32];       // 8 KB

    const int tid  = threadIdx.x;
    const int w    = tid >> 6;
    const int lane = tid & 63;
    const int wm = w >> 1, wn = w & 1;
    const int m0 = blockIdx.x * 128;
    const int n0 = blockIdx.y * 128;

    f32x4 acc[4][4];
    #pragma unroll
    for (int a = 0; a < 4; ++a)
        #pragma unroll
        for (int b = 0; b < 4; ++b)
            acc[a][b] = (f32x4){0.f, 0.f, 0.f, 0.f};

    const int lrow = lane >> 2;
    const int lcol = (lane & 3) * 8;

    const __bf16* Ag0 = A  + (size_t)(m0 + w * 32 + lrow) * Kd + lcol;
    const __bf16* Ag1 = A  + (size_t)(m0 + w * 32 + 16 + lrow) * Kd + lcol;
    const __bf16* Bg0 = Wm + (size_t)(n0 + w * 32 + lrow) * Kd + lcol;
    const __bf16* Bg1 = Wm + (size_t)(n0 + w * 32 + 16 + lrow) * Kd + lcol;
    __bf16* Al0 = &As[(w * 32) * 32];
    __bf16* Al1 = &As[(w * 32 + 16) * 32];
    __bf16* Bl0 = &Bs[(w * 32) * 32];
    __bf16* Bl1 = &Bs[(w * 32 + 16) * 32];

    const int fr = lane & 15;
    const int fq = (lane >> 4) * 8;

    for (int kt = 0; kt < Kd; kt += 32) {
        gld16(Ag0 + kt, Al0);
        gld16(Ag1 + kt, Al1);
        gld16(Bg0 + kt, Bl0);
        gld16(Bg1 + kt, Bl1);
        __syncthreads();
        bf16x8 af[4], bf[4];
        #pragma unroll
        for (int t = 0; t < 4; ++t) {
            af[t] = *(const bf16x8*)(&As[(wm * 64 + t * 16 + fr) * 32 + fq]);
            bf[t] = *(const bf16x8*)(&Bs[(wn * 64 + t * 16 + fr) * 32 + fq]);
        }
        #pragma unroll
        for (int mt = 0; mt < 4; ++mt)
            #pragma unroll
            for (int nt = 0; nt < 4; ++nt)
                acc[mt][nt] = __builtin_amdgcn_mfma_f32_16x16x32_bf16(af[mt], bf[nt], acc[mt][nt], 0, 0, 0);
        __syncthreads();
    }

    const int col   = lane & 15;
    const int rbase = (lane >> 4) * 4;
    #pragma unroll
    for (int nt = 0; nt < 4; ++nt) {
        const int cc = n0 + wn * 64 + nt * 16 + col;
        const float bv = bias[cc];
        #pragma unroll
        for (int mt = 0; mt < 4; ++mt) {
            #pragma unroll
            for (int r = 0; r < 4; ++r) {
                const int row = m0 + wm * 64 + mt * 16 + rbase + r;
                const float v = acc[mt][nt][r] + bv;
                if (Cf) Cf[(size_t)row * N + cc] = v;
                if (Cb) Cb[(size_t)row * N + cc] = (__bf16)v;
            }
        }
    }
}

// ---------------------------------------------------------------------------
// fp32 NT GEMM (kept for logits, N=8)
// ---------------------------------------------------------------------------
__global__ __launch_bounds__(256)
void gemm_nt(const float* __restrict__ A, const float* __restrict__ Bm,
             const float* __restrict__ bias, float* __restrict__ C,
             int M, int N, int Kd)
{
    __shared__ __align__(16) float As[16][68];
    __shared__ __align__(16) float Bsh[16][68];

    const int tid = threadIdx.x;
    const int tx = tid & 15, ty = tid >> 4;
    const int m0 = blockIdx.x * 64;
    const int n0 = blockIdx.y * 64;

    float acc[4][4] = {{0.f}};
    const int lm = tid >> 2;
    const int lk = (tid & 3) * 4;
    const int arow = m0 + lm;
    const int brow = n0 + lm;
    const bool aval = arow < M;
    const bool bval = brow < N;
    const float* Ap = A  + (size_t)arow * Kd + lk;
    const float* Bp = Bm + (size_t)brow * Kd + lk;

    for (int kt = 0; kt < Kd; kt += 16) {
        float4 a = aval ? *(const float4*)(Ap + kt) : make_float4(0.f, 0.f, 0.f, 0.f);
        float4 b = bval ? *(const float4*)(Bp + kt) : make_float4(0.f, 0.f, 0.f, 0.f);
        As[lk+0][lm] = a.x; As[lk+1][lm] = a.y; As[lk+2][lm] = a.z; As[lk+3][lm] = a.w;
        Bsh[lk+0][lm] = b.x; Bsh[lk+1][lm] = b.y; Bsh[lk+2][lm] = b.z; Bsh[lk+3][lm] = b.w;
        __syncthreads();
        #pragma unroll
        for (int kk = 0; kk < 16; ++kk) {
            const float4 av = *(const float4*)(&As[kk][ty * 4]);
            const float4 bvv = *(const float4*)(&Bsh[kk][tx * 4]);
            const float aa[4] = {av.x, av.y, av.z, av.w};
            const float bb[4] = {bvv.x, bvv.y, bvv.z, bvv.w};
            #pragma unroll
            for (int i = 0; i < 4; ++i)
                #pragma unroll
                for (int j = 0; j < 4; ++j)
                    acc[i][j] = fmaf(aa[i], bb[j], acc[i][j]);
        }
        __syncthreads();
    }

    #pragma unroll
    for (int i = 0; i < 4; ++i) {
        const int r = m0 + ty * 4 + i;
        if (r >= M) continue;
        #pragma unroll
        for (int j = 0; j < 4; ++j) {
            const int c = n0 + tx * 4 + j;
            if (c < N) C[(size_t)r * N + c] = acc[i][j] + bias[c];
        }
    }
}

// ---------------------------------------------------------------------------
__device__ __forceinline__ void block_sum2(float& s, float& s2, float* red, int tid)
{
    #pragma unroll
    for (int off = 32; off > 0; off >>= 1) {
        s  += __shfl_down(s,  off);
        s2 += __shfl_down(s2, off);
    }
    const int wid = tid >> 6;
    if ((tid & 63) == 0) { red[wid] = s; red[4 + wid] = s2; }
    __syncthreads();
    if (tid == 0) {
        float a = 0.f, b = 0.f;
        for (int i = 0; i < 4; ++i) { a += red[i]; b += red[4 + i]; }
        red[8] = a; red[9] = b;
    }
    __syncthreads();
    s = red[8]; s2 = red[9];
}

// LN over H per (b,k) row, in place + bf16 copy
__global__ __launch_bounds__(256)
void ln_expert_kernel(float* __restrict__ h, const float* __restrict__ g,
                      const float* __restrict__ bb, __bf16* __restrict__ hbf)
{
    __shared__ float red[10];
    const int row = blockIdx.x;
    const int k = row & (K_ - 1);
    const int tid = threadIdx.x;
    float* p = h + (size_t)row * H_;

    const float4 v = *(const float4*)(p + tid * 4);
    float s  = v.x + v.y + v.z + v.w;
    float s2 = v.x * v.x + v.y * v.y + v.z * v.z + v.w * v.w;
    block_sum2(s, s2, red, tid);
    const float mean = s * (1.0f / H_);
    const float var  = s2 * (1.0f / H_) - mean * mean;
    const float inv  = rsqrtf(var + 1e-5f);

    const float* gg = g  + (size_t)k * H_ + tid * 4;
    const float* bp = bb + (size_t)k * H_ + tid * 4;
    float4 o;
    o.x = (v.x - mean) * inv * gg[0] + bp[0];
    o.y = (v.y - mean) * inv * gg[1] + bp[1];
    o.z = (v.z - mean) * inv * gg[2] + bp[2];
    o.w = (v.w - mean) * inv * gg[3] + bp[3];
    *(float4*)(p + tid * 4) = o;
    bf16x4 ob; ob[0] = (__bf16)o.x; ob[1] = (__bf16)o.y; ob[2] = (__bf16)o.z; ob[3] = (__bf16)o.w;
    *(bf16x4*)(hbf + (size_t)row * H_ + tid * 4) = ob;
}

// context = LN(query + attn_out)
__global__ __launch_bounds__(256)
void add_ln_kernel(const float* __restrict__ q, const float* __restrict__ a,
                   const float* __restrict__ g, const float* __restrict__ bb,
                   float* __restrict__ out)
{
    __shared__ float red[10];
    const int row = blockIdx.x;
    const int tid = threadIdx.x;
    const float4 qv = *(const float4*)(q + (size_t)row * H_ + tid * 4);
    const float4 av = *(const float4*)(a + (size_t)row * H_ + tid * 4);
    float4 v = make_float4(qv.x + av.x, qv.y + av.y, qv.z + av.z, qv.w + av.w);
    float s  = v.x + v.y + v.z + v.w;
    float s2 = v.x * v.x + v.y * v.y + v.z * v.z + v.w * v.w;
    block_sum2(s, s2, red, tid);
    const float mean = s * (1.0f / H_);
    const float var  = s2 * (1.0f / H_) - mean * mean;
    const float inv  = rsqrtf(var + 1e-5f);
    const float* gg = g  + tid * 4;
    const float* bp = bb + tid * 4;
    float4 o;
    o.x = (v.x - mean) * inv * gg[0] + bp[0];
    o.y = (v.y - mean) * inv * gg[1] + bp[1];
    o.z = (v.z - mean) * inv * gg[2] + bp[2];
    o.w = (v.w - mean) * inv * gg[3] + bp[3];
    *(float4*)(out + (size_t)row * H_ + tid * 4) = o;
}

// ---------------------------------------------------------------------------
// Attention over K=8 experts, NH=4 heads of HD=256; bf16 K/V, fp32 Q; bf16 ctx.
// ---------------------------------------------------------------------------
__global__ __launch_bounds__(256)
void attn_kernel(const float* __restrict__ q, const __bf16* __restrict__ kb,
                 const __bf16* __restrict__ vb, __bf16* __restrict__ ctx)
{
    __shared__ __align__(16) float qs[H_];
    __shared__ float sc[NH_ * K_];
    __shared__ float aw[NH_ * K_];
    const int b = blockIdx.x;
    const int tid = threadIdx.x;

    *(float4*)(&qs[tid * 4]) = *(const float4*)(q + (size_t)b * H_ + tid * 4);
    __syncthreads();

    const int pair = tid >> 3;
    const int l8 = tid & 7;
    const int nh = pair >> 3;
    const int kx = pair & 7;
    float partial = 0.f;
    const __bf16* kr = kb + ((size_t)b * K_ + kx) * H_ + nh * HD_;
    #pragma unroll
    for (int t = 0; t < 4; ++t) {
        const int off = (l8 + t * 8) * 8;
        const bf16x8 kk = *(const bf16x8*)(kr + off);
        const float4 qa = *(const float4*)(&qs[nh * HD_ + off]);
        const float4 qb = *(const float4*)(&qs[nh * HD_ + off + 4]);
        partial += qa.x * (float)kk[0] + qa.y * (float)kk[1] + qa.z * (float)kk[2] + qa.w * (float)kk[3];
        partial += qb.x * (float)kk[4] + qb.y * (float)kk[5] + qb.z * (float)kk[6] + qb.w * (float)kk[7];
    }
    partial += __shfl_down(partial, 4, 8);
    partial += __shfl_down(partial, 2, 8);
    partial += __shfl_down(partial, 1, 8);
    if (l8 == 0) sc[pair] = partial * (1.0f / 16.0f);
    __syncthreads();

    if (tid < NH_) {
        float m = -1e30f;
        for (int j = 0; j < K_; ++j) m = fmaxf(m, sc[tid * K_ + j]);
        float e[K_]; float ssum = 0.f;
        for (int j = 0; j < K_; ++j) { e[j] = __expf(sc[tid * K_ + j] - m); ssum += e[j]; }
        const float invs = 1.0f / ssum;
        for (int j = 0; j < K_; ++j) aw[tid * K_ + j] = e[j] * invs;
    }
    __syncthreads();

    const int e0 = tid * 4;
    const int nh2 = e0 >> 8;
    float4 acc = make_float4(0.f, 0.f, 0.f, 0.f);
    #pragma unroll
    for (int j = 0; j < K_; ++j) {
        const float ww = aw[nh2 * K_ + j];
        const bf16x4 v4 = *(const bf16x4*)(vb + ((size_t)b * K_ + j) * H_ + e0);
        acc.x += ww * (float)v4[0]; acc.y += ww * (float)v4[1];
        acc.z += ww * (float)v4[2]; acc.w += ww * (float)v4[3];
    }
    bf16x4 o; o[0] = (__bf16)acc.x; o[1] = (__bf16)acc.y; o[2] = (__bf16)acc.z; o[3] = (__bf16)acc.w;
    *(bf16x4*)(ctx + (size_t)b * H_ + e0) = o;
}

__global__ __launch_bounds__(256)
void gate_softmax_kernel(const float* __restrict__ logits, float* __restrict__ g)
{
    const int b = blockIdx.x * blockDim.x + threadIdx.x;
    if (b >= B_) return;
    float v[K_];
    float m = -1e30f;
    #pragma unroll
    for (int j = 0; j < K_; ++j) { v[j] = logits[(size_t)b * K_ + j]; m = fmaxf(m, v[j]); }
    float ssum = 0.f;
    #pragma unroll
    for (int j = 0; j < K_; ++j) { v[j] = __expf(v[j] - m); ssum += v[j]; }
    const float invs = 1.0f / ssum;
    #pragma unroll
    for (int j = 0; j < K_; ++j) g[(size_t)b * K_ + j] = v[j] * invs;
}

// mixed[b,h] = sum_k g[b,k] * h_new[b,k,h]  (bf16 out)
__global__ __launch_bounds__(256)
void mixed_kernel(const float* __restrict__ g, const float* __restrict__ h,
                  __bf16* __restrict__ mixed)
{
    __shared__ float gs[K_];
    const int b = blockIdx.x;
    const int tid = threadIdx.x;
    if (tid < K_) gs[tid] = g[(size_t)b * K_ + tid];
    __syncthreads();
    const int e0 = tid * 4;
    float4 acc = make_float4(0.f, 0.f, 0.f, 0.f);
    #pragma unroll
    for (int j = 0; j < K_; ++j) {
        const float w = gs[j];
        const float4 v4 = *(const float4*)(h + ((size_t)b * K_ + j) * H_ + e0);
        acc.x += w * v4.x; acc.y += w * v4.y; acc.z += w * v4.z; acc.w += w * v4.w;
    }
    bf16x4 o; o[0] = (__bf16)acc.x; o[1] = (__bf16)acc.y; o[2] = (__bf16)acc.z; o[3] = (__bf16)acc.w;
    *(bf16x4*)(mixed + (size_t)b * H_ + e0) = o;
}

// ---------------------------------------------------------------------------
extern "C" void kernel_launch(void* const* d_in, const int* in_sizes, int n_in,
                              void* d_out, int out_size, void* d_ws, size_t ws_size,
                              hipStream_t stream)
{
    (void)in_sizes; (void)n_in; (void)out_size; (void)ws_size;

    const float* x    = (const float*)d_in[0];
    const float* hp   = (const float*)d_in[1];
    const float* Wih  = (const float*)d_in[2];
    const float* Whh  = (const float*)d_in[3];
    const float* bih  = (const float*)d_in[4];
    const float* bhh  = (const float*)d_in[5];
    const float* lng  = (const float*)d_in[6];
    const float* lnb  = (const float*)d_in[7];
    const float* Wqp  = (const float*)d_in[8];
    const float* bqp  = (const float*)d_in[9];
    const float* Wq   = (const float*)d_in[10];
    const float* Wk   = (const float*)d_in[11];
    const float* Wv   = (const float*)d_in[12];
    const float* bq   = (const float*)d_in[13];
    const float* bk   = (const float*)d_in[14];
    const float* bv   = (const float*)d_in[15];
    const float* Wo   = (const float*)d_in[16];
    const float* bo   = (const float*)d_in[17];
    const float* alng = (const float*)d_in[18];
    const float* alnb = (const float*)d_in[19];
    const float* Wg   = (const float*)d_in[20];
    const float* bg   = (const float*)d_in[21];
    const float* Wr   = (const float*)d_in[22];
    const float* br   = (const float*)d_in[23];

    float* h_new  = (float*)d_out;                         // (B,K,H)
    float* y_hat  = h_new + (size_t)B_ * K_ * H_;          // (B,O)
    float* g_t    = y_hat + (size_t)B_ * O_;               // (B,K)
    float* logits = g_t + (size_t)B_ * K_;                 // (B,K)

    // ---- workspace layout (~316 MB), with lifetime-based aliasing ----
    char* Wp = (char*)d_ws;
    auto alloc = [&](size_t bytes) { char* p = Wp; Wp += (bytes + 255) & ~(size_t)255; return p; };

    const size_t nBKH = (size_t)B_ * K_ * H_;   // 33,554,432
    const size_t nBH  = (size_t)B_ * H_;        //  4,194,304
    const size_t nWih = (size_t)K_ * H3_ * D_;  // 12,582,912
    const size_t nWhh = (size_t)K_ * H3_ * H_;  // 25,165,824

    __bf16* hp_bf   = (__bf16*)alloc(nBKH * 2);            // dead after GRU -> vbuf
    __bf16* vbuf    = hp_bf;
    __bf16* Wih_bf  = (__bf16*)alloc((nWih + nWhh) * 2);   // dead after GRU -> kbuf
    __bf16* Whh_bf  = Wih_bf + nWih;
    __bf16* kbuf    = Wih_bf;
    __bf16* x_bf    = (__bf16*)alloc((size_t)B_ * D_ * 2);
    __bf16* hln_bf  = (__bf16*)alloc(nBKH * 2);
    float*  query   = (float*)alloc(nBH * 4);
    float*  qbuf    = (float*)alloc(nBH * 4);
    float*  attno   = (float*)alloc(nBH * 4);
    float*  contx   = (float*)alloc(nBH * 4);
    __bf16* query_bf= (__bf16*)alloc(nBH * 2);
    __bf16* ctx_bf  = (__bf16*)alloc(nBH * 2);
    __bf16* mixed_bf= (__bf16*)alloc(nBH * 2);
    __bf16* Wqp_bf  = (__bf16*)alloc((size_t)H_ * D_ * 2);
    __bf16* Wq_bf   = (__bf16*)alloc((size_t)H_ * H_ * 2);
    __bf16* Wk_bf   = (__bf16*)alloc((size_t)H_ * H_ * 2);
    __bf16* Wv_bf   = (__bf16*)alloc((size_t)H_ * H_ * 2);
    __bf16* Wo_bf   = (__bf16*)alloc((size_t)H_ * H_ * 2);
    __bf16* Wr_bf   = (__bf16*)alloc((size_t)O_ * H_ * 2);

    const dim3 blk(256);
    auto cast = [&](const float* src, __bf16* dst, size_t n) {
        cast_kernel<<<dim3((unsigned)(n / 8 / 256)), blk, 0, stream>>>(src, dst, (long)n);
    };

    // ---- casts ----
    cast(x,   x_bf,   (size_t)B_ * D_);
    cast(hp,  hp_bf,  nBKH);
    cast(Wih, Wih_bf, nWih);
    cast(Whh, Whh_bf, nWhh);
    cast(Wqp, Wqp_bf, (size_t)H_ * D_);
    cast(Wq,  Wq_bf,  (size_t)H_ * H_);
    cast(Wk,  Wk_bf,  (size_t)H_ * H_);
    cast(Wv,  Wv_bf,  (size_t)H_ * H_);
    cast(Wo,  Wo_bf,  (size_t)H_ * H_);
    cast(Wr,  Wr_bf,  (size_t)O_ * H_);

    // ---- GRU (MFMA) + per-expert LN ----
    gru_mfma_kernel<<<dim3(B_ / 64, H_ / 64, K_), blk, 0, stream>>>(
        x_bf, hp_bf, Wih_bf, Whh_bf, bih, bhh, hp, h_new);
    ln_expert_kernel<<<dim3(B_ * K_), blk, 0, stream>>>(h_new, lng, lnb, hln_bf);

    // ---- projections (MFMA) ----
    gemm_mfma<<<dim3(B_ / 128, H_ / 128), blk, 0, stream>>>(x_bf, Wqp_bf, bqp, query, query_bf, B_, H_, D_);
    gemm_mfma<<<dim3(B_ / 128, H_ / 128), blk, 0, stream>>>(query_bf, Wq_bf, bq, qbuf, nullptr, B_, H_, H_);
    gemm_mfma<<<dim3(B_ * K_ / 128, H_ / 128), blk, 0, stream>>>(hln_bf, Wk_bf, bk, nullptr, kbuf, B_ * K_, H_, H_);
    gemm_mfma<<<dim3(B_ * K_ / 128, H_ / 128), blk, 0, stream>>>(hln_bf, Wv_bf, bv, nullptr, vbuf, B_ * K_, H_, H_);

    // ---- attention + out projection + add&LN ----
    attn_kernel<<<dim3(B_), blk, 0, stream>>>(qbuf, kbuf, vbuf, ctx_bf);
    gemm_mfma<<<dim3(B_ / 128, H_ / 128), blk, 0, stream>>>(ctx_bf, Wo_bf, bo, attno, nullptr, B_, H_, H_);
    add_ln_kernel<<<dim3(B_), blk, 0, stream>>>(query, attno, alng, alnb, contx);

    // ---- gating + readout ----
    gemm_nt<<<dim3(B_ / 64, 1), blk, 0, stream>>>(contx, Wg, bg, logits, B_, K_, H_);
    gate_softmax_kernel<<<dim3(B_ / 256), blk, 0, stream>>>(logits, g_t);
    mixed_kernel<<<dim3(B_), blk, 0, stream>>>(g_t, h_new, mixed_bf);
    gemm_mfma<<<dim3(B_ / 128, O_ / 128), blk, 0, stream>>>(mixed_bf, Wr_bf, br, y_hat, nullptr, B_, O_, H_);
}